// Round 17
// baseline (207.612 us; speedup 1.0000x reference)
//
#include <hip/hip_runtime.h>
#include <cmath>

// ---------------- problem constants ----------------
#define SNUM 6
#define CNUM 128
#define HF 56
#define WF 100
#define HW (HF*WF)          // 5600
#define ZN 128
#define YN 8
#define XN 128
#define NVOX (ZN*YN*XN)     // 131072

typedef __attribute__((ext_vector_type(8))) short bf16x8;
typedef __attribute__((ext_vector_type(4))) float f32x4;
typedef __attribute__((ext_vector_type(4))) int   i32x4;

__device__ __forceinline__ unsigned short f2bf(float f) {
    unsigned u = __builtin_bit_cast(unsigned, f);
    unsigned r = (u + 0x7FFFu + ((u >> 16) & 1u)) >> 16;   // RNE
    return (unsigned short)r;
}
__device__ __forceinline__ float bf2f(unsigned short h) {
    unsigned u = (unsigned)h << 16;
    return __builtin_bit_cast(float, u);
}

// async global->LDS: dest = uniform base + lane*size; src per-lane
__device__ __forceinline__ void gl_lds16(const void* g, void* l) {
    __builtin_amdgcn_global_load_lds(
        (const __attribute__((address_space(1))) void*)g,
        (__attribute__((address_space(3))) void*)l, 16, 0, 0);
}
__device__ __forceinline__ void gl_lds4(const void* g, void* l) {
    __builtin_amdgcn_global_load_lds(
        (const __attribute__((address_space(1))) void*)g,
        (__attribute__((address_space(3))) void*)l, 4, 0, 0);
}

// ---------------- setup: per-camera matrices ----------------
__global__ void k_setup(const float* __restrict__ intrins,
                        const float* __restrict__ rots,
                        const float* __restrict__ trans,
                        float* __restrict__ mats) {
    int s = threadIdx.x;
    if (s >= SNUM) return;
    float R0[9], Rs[9], t0[3], ts[3];
    for (int i = 0; i < 9; ++i) { R0[i] = rots[i]; Rs[i] = rots[s*9 + i]; }
    for (int i = 0; i < 3; ++i) { t0[i] = trans[i]; ts[i] = trans[s*3 + i]; }
    float M[3][4];
    float d0 = t0[0]-ts[0], d1 = t0[1]-ts[1], d2 = t0[2]-ts[2];
    for (int i = 0; i < 3; ++i) {
        for (int j = 0; j < 3; ++j)
            M[i][j] = Rs[0*3+i]*R0[0*3+j] + Rs[1*3+i]*R0[1*3+j] + Rs[2*3+i]*R0[2*3+j];
        M[i][3] = Rs[0*3+i]*d0 + Rs[1*3+i]*d1 + Rs[2*3+i]*d2;
    }
    const float sx = (float)WF/800.0f, sy = (float)HF/448.0f;
    float fx = intrins[s*16 + 0]*sx, fy = intrins[s*16 + 5]*sy;
    float cx = intrins[s*16 + 2]*sx, cy = intrins[s*16 + 6]*sy;
    float* o = mats + s*24;
    for (int j = 0; j < 4; ++j) {
        o[0*4+j]      = M[0][j];
        o[1*4+j]      = M[1][j];
        o[2*4+j]      = M[2][j];
        o[12 + 0*4+j] = fx*M[0][j] + cx*M[2][j];
        o[12 + 1*4+j] = fy*M[1][j] + cy*M[2][j];
        o[12 + 2*4+j] = M[2][j];
    }
}

// ---------------- transpose cam_feat (S,C,HW) f32 -> featT (S,HW,C) bf16 -------
__global__ __launch_bounds__(256) void k_tfeat(const float* __restrict__ cf,
                                               unsigned short* __restrict__ featT) {
    __shared__ float t[32][33];
    int s = blockIdx.z;
    int p0 = blockIdx.x * 32, c0 = blockIdx.y * 32;
    int tx = threadIdx.x, ty = threadIdx.y;   // 32 x 8
#pragma unroll
    for (int k = 0; k < 4; ++k) {
        int r = ty + k*8;
        t[r][tx] = cf[((size_t)s*CNUM + c0 + r)*HW + p0 + tx];
    }
    __syncthreads();
#pragma unroll
    for (int k = 0; k < 4; ++k) {
        int r = ty + k*8;
        featT[((size_t)s*HW + p0 + r)*CNUM + c0 + tx] = f2bf(t[tx][r]);
    }
}

// ---------------- zero the pad regions of bevin2 ----------------
__global__ __launch_bounds__(256) void k_zero(unsigned short* __restrict__ bevin2) {
    int i = blockIdx.x*256 + threadIdx.x;
    if (i >= 66048) return;
    size_t unit;
    if (i < 33280) {
        int zr = i / 16640;            // 0 or 1
        int j  = i - zr*16640;
        unit = (size_t)(zr ? 129 : 0)*16640 + j;
    } else {
        int j  = i - 33280;            // [0, 32768)
        int zp = 1 + (j >> 8);         // z' in [1,129)
        int r  = j & 255;
        int c  = r >> 1;
        int xp = (r & 1) ? 129 : 0;
        unit = ((size_t)zp*128 + c)*130 + xp;
    }
    *(i32x4*)&bevin2[unit*8] = i32x4{0,0,0,0};
}

// ---------------- fused projection + bilinear sample + masked mean -> bevin2 ----
__global__ __launch_bounds__(256) void k_sample(const unsigned short* __restrict__ featT,
                                                const float* __restrict__ mats,
                                                unsigned short* __restrict__ bevin2) {
#pragma clang fp contract(off)
    __shared__ float xch[16][132];        // [vs = y*2+xs][c]
    __shared__ float2 suv[16][6];         // per-voxel per-cam (ux,uy)
    const int tid = threadIdx.x;
    const int b = blockIdx.x;             // 8192 = 128 z * 64 x-pairs
    const int z = b >> 6, x0 = (b & 63) * 2;
    const int cl = tid & 15, vs = tid >> 4;
    // ---- inline projection (exact k_geo arithmetic), 96 threads ----
    if (tid < 96) {
        int v = tid / 6, s = tid - (tid/6)*6;
        int yi = v >> 1, xi2 = x0 + (v & 1);
        float xr = -49.609375f + (float)xi2 * 0.78125f;
        float yr = (-4.9f + 0.625f) + (float)yi * 1.25f;
        float zr = -49.609375f + (float)z * 0.78125f;
        const float* m = mats + s*24;
        float zc = m[8]*xr  + m[9]*yr  + m[10]*zr + m[11];
        float ph = m[12]*xr + m[13]*yr + m[14]*zr + m[15];
        float qh = m[16]*xr + m[17]*yr + m[18]*zr + m[19];
        float denom = fmaxf(zc, 1e-6f);
        float px = ph / denom, py = qh / denom;
        bool valid = (px > -0.5f) & (px < (float)WF - 0.5f) &
                     (py > -0.5f) & (py < (float)HF - 0.5f) & (zc > 0.0f);
        float ux = -10000.0f, uy = -10000.0f;
        if (valid) {
            float gx = 2.0f*px/((float)WF - 1.0f) - 1.0f;
            float gy = 2.0f*py/((float)HF - 1.0f) - 1.0f;
            gx = fminf(fmaxf(gx, -2.0f), 2.0f);
            gy = fminf(fmaxf(gy, -2.0f), 2.0f);
            ux = ((gx + 1.0f)*(float)WF - 1.0f)*0.5f;
            uy = ((gy + 1.0f)*(float)HF - 1.0f)*0.5f;
        }
        suv[v][s] = float2{ux, uy};
    }
    __syncthreads();

    const bf16x8 zz8 = {0,0,0,0,0,0,0,0};
    float sum[8], cnt[8];
#pragma unroll
    for (int k = 0; k < 8; ++k) { sum[k] = 0.0f; cnt[k] = 0.0f; }
    for (int s = 0; s < SNUM; ++s) {
        float2 u = suv[vs][s];
        if (u.x < -999.0f) continue;
        float x0f = floorf(u.x), y0f = floorf(u.y);
        float wx = u.x - x0f, wy = u.y - y0f;
        int ix = (int)x0f, iy = (int)y0f;
        float w00 = (1.0f-wx)*(1.0f-wy), w10 = wx*(1.0f-wy);
        float w01 = (1.0f-wx)*wy,        w11 = wx*wy;
        bool bx0 = (ix >= 0) & (ix < WF);
        bool bx1 = (ix >= -1) & (ix < WF-1);
        bool by0 = (iy >= 0) & (iy < HF);
        bool by1 = (iy >= -1) & (iy < HF-1);
        bool c00 = bx0 & by0, c10 = bx1 & by0, c01 = bx0 & by1, c11 = bx1 & by1;
        const unsigned short* fb = featT + (size_t)s * (HW*CNUM) + cl*8;
        long r0 = (long)(iy*WF + ix) * CNUM;
        bf16x8 v00 = c00 ? *(const bf16x8*)(fb + r0)                 : zz8;
        bf16x8 v10 = c10 ? *(const bf16x8*)(fb + r0 + CNUM)          : zz8;
        bf16x8 v01 = c01 ? *(const bf16x8*)(fb + r0 + WF*CNUM)       : zz8;
        bf16x8 v11 = c11 ? *(const bf16x8*)(fb + r0 + WF*CNUM + CNUM): zz8;
#pragma unroll
        for (int k = 0; k < 8; ++k) {
            float v = 0.0f;
            v = v + w00 * bf2f((unsigned short)v00[k]);
            v = v + w10 * bf2f((unsigned short)v10[k]);
            v = v + w01 * bf2f((unsigned short)v01[k]);
            v = v + w11 * bf2f((unsigned short)v11[k]);
            sum[k] += v;
            cnt[k] += (v != 0.0f) ? 1.0f : 0.0f;
        }
    }
#pragma unroll
    for (int k = 0; k < 8; ++k)
        xch[vs][cl*8 + k] = sum[k] / (1e-6f + cnt[k]);
    __syncthreads();
    // pack: thread t -> channel c = t>>1, xs2 = t&1; one 16B unit (y=0..7)
    {
        int c = tid >> 1, xs2 = tid & 1;
        unsigned pk[4];
#pragma unroll
        for (int j = 0; j < 4; ++j) {
            float v0 = xch[(2*j)*2 + xs2][c];
            float v1 = xch[(2*j+1)*2 + xs2][c];
            pk[j] = (unsigned)f2bf(v0) | ((unsigned)f2bf(v1) << 16);
        }
        size_t unit = ((size_t)(z+1)*128 + c)*130 + (x0 + xs2 + 1);
        *(i32x4*)&bevin2[unit*8] = i32x4{(int)pk[0], (int)pk[1], (int)pk[2], (int)pk[3]};
    }
}

// ---------------- weight prep: conv_w [co][ci][3][3] f32 -> w2 [tap][co][ci] bf16 ----
__global__ __launch_bounds__(256) void k_wprep(const float* __restrict__ w,
                                               unsigned short* __restrict__ w2) {
    int i = blockIdx.x*256 + threadIdx.x;     // over 9*128*1024
    if (i >= 9*128*1024) return;
    int ci = i & 1023; int rest = i >> 10; int co = rest & 127; int tap = rest >> 7;
    w2[i] = f2bf(w[((size_t)co*1024 + ci)*9 + tap]);
}

// ---------------- MFMA conv 3x3: full 8-phase-template port ------------------
// grid 256 (XCD-swizzled) = 128z x 2coh, 1 block/CU. Block = 512 thr = 8 waves
// (2 co-rows x 4 x-quarters) -> 2 waves/SIMD IN LOCKSTEP PHASES. Tile 64co x
// 128x, BK=32, FOUR LDS bufs, stage 2 steps ahead. Per step: 3 tap-phases of
// {A-loads -> stage quota -> s_barrier -> setprio(1) 12xMFMA setprio(0) ->
// s_barrier}; counted vmcnt(11) only at step boundaries (A-loads issued BEFORE
// stage instrs so compiler A-waits keep the stage queue in flight).
__global__ __launch_bounds__(512, 2) void k_conv_mfma(
        const unsigned short* __restrict__ bevin2,  // [130 z'][128 c][130 x'][8] bf16
        const unsigned short* __restrict__ w2,      // [tap][co][1024] bf16
        float* __restrict__ out,
        float* __restrict__ psum, float* __restrict__ psq) {
    // [buf 0..3][row = dz*4 + cq][144 units][8]; units 0..129 real
    __shared__ __align__(16) unsigned short lds[4][12*144*8];
    const int tid  = threadIdx.x;                   // 0..511
    const int bid  = blockIdx.x;
    const int swz  = (bid & 7)*32 + (bid >> 3);     // XCD-contiguous (z,coh)
    const int z0   = swz & 127;
    const int coh  = swz >> 7;
    const int lane = tid & 63, wid = tid >> 6;      // 8 waves
    const int wr = wid >> 2, xw = wid & 3;          // co-row (2), x-quarter (4)
    const int co_base = coh*64 + wr*32;
    const int l15 = lane & 15, lhi = lane >> 4;
    const int sphase = wid % 3;                     // which phase this wave stages in

    f32x4 acc[2][2];
#pragma unroll
    for (int f = 0; f < 2; ++f)
#pragma unroll
        for (int nf = 0; nf < 2; ++nf) acc[f][nf] = f32x4{0.f,0.f,0.f,0.f};

    const unsigned short* aw0 = w2 + ((size_t)(co_base      + l15))*1024 + lhi*8;
    const unsigned short* aw1 = w2 + ((size_t)(co_base + 16 + l15))*1024 + lhi*8;

    bf16x8 aC[6], aN[6];      // rolling A: one dz-group (3 dx x 2 cf)

    // wave stages instrs j = wid + 8k (k=0..4, j<36); row=j/3, part=j%3
#define STG(SS)                                                                \
    {                                                                          \
        _Pragma("unroll")                                                      \
        for (int k = 0; k < 5; ++k) {                                          \
            int j = wid + 8*k;                                                 \
            if (j < 36) {                                                      \
                int r = j/3, part = j - r*3;                                   \
                int zrel = r >> 2, cq = r & 3;                                 \
                const unsigned short* gsrc = bevin2 +                          \
                    (((size_t)(z0 + zrel)*128 + (SS)*4 + cq)*130)*8;           \
                unsigned short* ldst = &lds[(SS) & 3][r*144*8];                \
                if (part == 0)      gl_lds16(gsrc + (size_t)lane*8, ldst);     \
                else if (part == 1) gl_lds16(gsrc + (size_t)(64 + lane)*8, ldst + 64*8); \
                else                gl_lds4 (gsrc + 128*8 + (size_t)lane*2, ldst + 128*8); \
            }                                                                  \
        }                                                                      \
    }
// A loads for one dz-group (3 dx x 2 co-frags); CI0 = step*32
#define A6(DST, DZ, CI0)                                                       \
    {                                                                          \
        _Pragma("unroll")                                                      \
        for (int t = 0; t < 3; ++t) {                                          \
            DST[t*2+0] = *(const bf16x8*)(aw0 + (size_t)((DZ)*3+t)*131072 + (CI0)); \
            DST[t*2+1] = *(const bf16x8*)(aw1 + (size_t)((DZ)*3+t)*131072 + (CI0)); \
        }                                                                      \
    }
// one phase: 3 dx x 2 nf x 2 cf = 12 MFMA, 6 ds_read, branch-free
#define MM(DZ, BUF, AFR)                                                       \
    {                                                                          \
        __builtin_amdgcn_s_setprio(1);                                         \
        _Pragma("unroll")                                                      \
        for (int dx = 0; dx < 3; ++dx) {                                       \
            bf16x8 a0 = AFR[dx*2+0];                                           \
            bf16x8 a1 = AFR[dx*2+1];                                           \
            _Pragma("unroll")                                                  \
            for (int nf = 0; nf < 2; ++nf) {                                   \
                bf16x8 bfr = *(const bf16x8*)&lds[BUF][(((DZ)*4 + lhi)*144 + xw*32 + nf*16 + l15 + dx)*8]; \
                acc[0][nf] = __builtin_amdgcn_mfma_f32_16x16x32_bf16(a0, bfr, acc[0][nf], 0, 0, 0); \
                acc[1][nf] = __builtin_amdgcn_mfma_f32_16x16x32_bf16(a1, bfr, acc[1][nf], 0, 0, 0); \
            }                                                                  \
        }                                                                      \
        __builtin_amdgcn_s_setprio(0);                                         \
    }
#define BAR() __builtin_amdgcn_s_barrier()
// boundary wait: allow stage(s+2) (<=5) + last A6 (6) in flight
#define PIPE_WAIT()  asm volatile("s_waitcnt vmcnt(11)" ::: "memory")

    // prologue: stage steps 0,1; A dz0 of step 0; full drain once
    STG(0); STG(1);
    A6(aC, 0, 0);
    __syncthreads();

    // 32 steps of 32 ci, processed in pairs for A-register parity
    for (int p2 = 0; p2 < 16; ++p2) {
        const int s = 2*p2;
        // ---- step s (even): phases use aC,aN,aC
        PIPE_WAIT();
        A6(aN, 1, s*32);
        if (sphase == 0 && s + 2 < 32) STG(s + 2);
        BAR(); MM(0, (s & 3), aC); BAR();
        A6(aC, 2, s*32);
        if (sphase == 1 && s + 2 < 32) STG(s + 2);
        BAR(); MM(1, (s & 3), aN); BAR();
        A6(aN, 0, (s+1)*32);
        if (sphase == 2 && s + 2 < 32) STG(s + 2);
        BAR(); MM(2, (s & 3), aC); BAR();
        // ---- step s+1 (odd): phases use aN,aC,aN
        PIPE_WAIT();
        A6(aC, 1, (s+1)*32);
        if (sphase == 0 && s + 3 < 32) STG(s + 3);
        BAR(); MM(0, ((s+1) & 3), aN); BAR();
        A6(aN, 2, (s+1)*32);
        if (sphase == 1 && s + 3 < 32) STG(s + 3);
        BAR(); MM(1, ((s+1) & 3), aC); BAR();
        if (s + 2 < 32) A6(aC, 0, (s+2)*32);
        if (sphase == 2 && s + 3 < 32) STG(s + 3);
        BAR(); MM(2, ((s+1) & 3), aN); BAR();
    }

    // ---- store + instance-norm partials ----
    float ps[2][4], pq[2][4];
#pragma unroll
    for (int f = 0; f < 2; ++f)
#pragma unroll
        for (int r = 0; r < 4; ++r) { ps[f][r] = 0.0f; pq[f][r] = 0.0f; }
#pragma unroll
    for (int f = 0; f < 2; ++f)
#pragma unroll
        for (int nf = 0; nf < 2; ++nf)
#pragma unroll
            for (int r = 0; r < 4; ++r) {
                int co = co_base + f*16 + lhi*4 + r;
                float v = acc[f][nf][r];
                out[(size_t)co*16384 + z0*128 + xw*32 + nf*16 + l15] = v;
                ps[f][r] += v;
                pq[f][r] += v*v;
            }
#pragma unroll
    for (int f = 0; f < 2; ++f)
#pragma unroll
        for (int r = 0; r < 4; ++r) {
            float s = ps[f][r], q = pq[f][r];
#pragma unroll
            for (int m = 1; m < 16; m <<= 1) {
                s += __shfl_xor(s, m);
                q += __shfl_xor(q, m);
            }
            if (l15 == 0) {
                int co = co_base + f*16 + lhi*4 + r;
                int pb = z0*4 + xw;       // 512 partials per co
                psum[co*512 + pb] = s;
                psq [co*512 + pb] = q;
            }
        }
#undef STG
#undef A6
#undef MM
#undef BAR
#undef PIPE_WAIT
}

// ---------------- instance-norm stats from partials (512 per co) ----------------
__global__ __launch_bounds__(256) void k_stats(const float* __restrict__ psum,
                                               const float* __restrict__ psq,
                                               float* __restrict__ stats) {
    __shared__ float r1[256], r2[256];
    int co = blockIdx.x, tid = threadIdx.x;
    r1[tid] = psum[co*512 + tid] + psum[co*512 + 256 + tid];
    r2[tid] = psq [co*512 + tid] + psq [co*512 + 256 + tid];
    __syncthreads();
    for (int off = 128; off > 0; off >>= 1) {
        if (tid < off) { r1[tid] += r1[tid+off]; r2[tid] += r2[tid+off]; }
        __syncthreads();
    }
    if (tid == 0) {
        float mean = r1[0] * (1.0f/16384.0f);
        float var  = r2[0] * (1.0f/16384.0f) - mean*mean;
        stats[co*2]   = mean;
        stats[co*2+1] = rsqrtf(var + 1e-5f);
    }
}

// ---------------- normalize + exact GELU (in place) ----------------
__global__ __launch_bounds__(256) void k_gelu(float* __restrict__ out,
                                              const float* __restrict__ stats) {
    int i = blockIdx.x*256 + threadIdx.x;
    int co = i >> 14;
    float v = out[i];
    float r = (v - stats[co*2]) * stats[co*2+1];
    out[i] = 0.5f * r * (1.0f + erff(r * 0.70710678118654752f));
}

extern "C" void kernel_launch(void* const* d_in, const int* in_sizes, int n_in,
                              void* d_out, int out_size, void* d_ws, size_t ws_size,
                              hipStream_t stream) {
    const float* cam_feat = (const float*)d_in[0];
    const float* intrins  = (const float*)d_in[1];
    const float* rots     = (const float*)d_in[2];
    const float* trans    = (const float*)d_in[3];
    const float* conv_w   = (const float*)d_in[4];
    float* out = (float*)d_out;
    float* ws  = (float*)d_ws;

    float* mats  = ws;                                          // 160 f
    unsigned short* featT  = (unsigned short*)(ws + 160);       // 4,300,800 bf16
    unsigned short* bevin2 = featT + (size_t)SNUM*HW*CNUM;      // 17,305,600 bf16
    unsigned short* w2     = bevin2 + (size_t)130*128*130*8;    // 1,179,648 bf16
    float* psum  = (float*)(w2 + 9*128*1024);                   // 65536 f
    float* psq   = psum + 65536;                                // 65536 f
    float* stats = psq + 65536;                                 // 256 f
    // total ~46.5 MB

    hipLaunchKernelGGL(k_setup, dim3(1), dim3(64), 0, stream, intrins, rots, trans, mats);
    hipLaunchKernelGGL(k_tfeat, dim3(HW/32, CNUM/32, SNUM), dim3(32,8), 0, stream, cam_feat, featT);
    hipLaunchKernelGGL(k_wprep, dim3((9*128*1024 + 255)/256), dim3(256), 0, stream, conv_w, w2);
    hipLaunchKernelGGL(k_zero, dim3((66048 + 255)/256), dim3(256), 0, stream, bevin2);
    hipLaunchKernelGGL(k_sample, dim3(8192), dim3(256), 0, stream, featT, mats, bevin2);
    hipLaunchKernelGGL(k_conv_mfma, dim3(256), dim3(512), 0, stream, bevin2, w2, out, psum, psq);
    hipLaunchKernelGGL(k_stats, dim3(128), dim3(256), 0, stream, psum, psq, stats);
    hipLaunchKernelGGL(k_gelu, dim3(8192), dim3(256), 0, stream, out, stats);
}

// Round 18
// 130.245 us; speedup vs baseline: 1.5940x; 1.5940x over previous
//
#include <hip/hip_runtime.h>
#include <cmath>

// ---------------- problem constants ----------------
#define SNUM 6
#define CNUM 128
#define HF 56
#define WF 100
#define HW (HF*WF)          // 5600
#define ZN 128
#define YN 8
#define XN 128
#define NVOX (ZN*YN*XN)     // 131072

typedef __attribute__((ext_vector_type(8))) short bf16x8;
typedef __attribute__((ext_vector_type(4))) float f32x4;
typedef __attribute__((ext_vector_type(4))) int   i32x4;

__device__ __forceinline__ unsigned short f2bf(float f) {
    unsigned u = __builtin_bit_cast(unsigned, f);
    unsigned r = (u + 0x7FFFu + ((u >> 16) & 1u)) >> 16;   // RNE
    return (unsigned short)r;
}
__device__ __forceinline__ float bf2f(unsigned short h) {
    unsigned u = (unsigned)h << 16;
    return __builtin_bit_cast(float, u);
}

// async global->LDS: dest = uniform base + lane*size; src per-lane
__device__ __forceinline__ void gl_lds16(const void* g, void* l) {
    __builtin_amdgcn_global_load_lds(
        (const __attribute__((address_space(1))) void*)g,
        (__attribute__((address_space(3))) void*)l, 16, 0, 0);
}
__device__ __forceinline__ void gl_lds4(const void* g, void* l) {
    __builtin_amdgcn_global_load_lds(
        (const __attribute__((address_space(1))) void*)g,
        (__attribute__((address_space(3))) void*)l, 4, 0, 0);
}

// ---------------- setup: per-camera matrices ----------------
__global__ void k_setup(const float* __restrict__ intrins,
                        const float* __restrict__ rots,
                        const float* __restrict__ trans,
                        float* __restrict__ mats) {
    int s = threadIdx.x;
    if (s >= SNUM) return;
    float R0[9], Rs[9], t0[3], ts[3];
    for (int i = 0; i < 9; ++i) { R0[i] = rots[i]; Rs[i] = rots[s*9 + i]; }
    for (int i = 0; i < 3; ++i) { t0[i] = trans[i]; ts[i] = trans[s*3 + i]; }
    float M[3][4];
    float d0 = t0[0]-ts[0], d1 = t0[1]-ts[1], d2 = t0[2]-ts[2];
    for (int i = 0; i < 3; ++i) {
        for (int j = 0; j < 3; ++j)
            M[i][j] = Rs[0*3+i]*R0[0*3+j] + Rs[1*3+i]*R0[1*3+j] + Rs[2*3+i]*R0[2*3+j];
        M[i][3] = Rs[0*3+i]*d0 + Rs[1*3+i]*d1 + Rs[2*3+i]*d2;
    }
    const float sx = (float)WF/800.0f, sy = (float)HF/448.0f;
    float fx = intrins[s*16 + 0]*sx, fy = intrins[s*16 + 5]*sy;
    float cx = intrins[s*16 + 2]*sx, cy = intrins[s*16 + 6]*sy;
    float* o = mats + s*24;
    for (int j = 0; j < 4; ++j) {
        o[0*4+j]      = M[0][j];
        o[1*4+j]      = M[1][j];
        o[2*4+j]      = M[2][j];
        o[12 + 0*4+j] = fx*M[0][j] + cx*M[2][j];
        o[12 + 1*4+j] = fy*M[1][j] + cy*M[2][j];
        o[12 + 2*4+j] = M[2][j];
    }
}

// ---------------- transpose cam_feat (S,C,HW) f32 -> featT (S,HW,C) bf16 -------
__global__ __launch_bounds__(256) void k_tfeat(const float* __restrict__ cf,
                                               unsigned short* __restrict__ featT) {
    __shared__ float t[32][33];
    int s = blockIdx.z;
    int p0 = blockIdx.x * 32, c0 = blockIdx.y * 32;
    int tx = threadIdx.x, ty = threadIdx.y;   // 32 x 8
#pragma unroll
    for (int k = 0; k < 4; ++k) {
        int r = ty + k*8;
        t[r][tx] = cf[((size_t)s*CNUM + c0 + r)*HW + p0 + tx];
    }
    __syncthreads();
#pragma unroll
    for (int k = 0; k < 4; ++k) {
        int r = ty + k*8;
        featT[((size_t)s*HW + p0 + r)*CNUM + c0 + tx] = f2bf(t[tx][r]);
    }
}

// ---------------- weight prep + pad-zeroing fused ----------------
// blocks [0, 4608): wprep over 9*128*1024; blocks [4608, 4866): zero 66048 pads
__global__ __launch_bounds__(256) void k_prep(const float* __restrict__ w,
                                              unsigned short* __restrict__ w2,
                                              unsigned short* __restrict__ bevin2) {
    int b = blockIdx.x;
    if (b < 4608) {
        int i = b*256 + threadIdx.x;          // over 9*128*1024
        int ci = i & 1023; int rest = i >> 10; int co = rest & 127; int tap = rest >> 7;
        w2[i] = f2bf(w[((size_t)co*1024 + ci)*9 + tap]);
    } else {
        int i = (b - 4608)*256 + threadIdx.x;
        if (i >= 66048) return;
        size_t unit;
        if (i < 33280) {
            int zr = i / 16640;               // 0 or 1
            int j  = i - zr*16640;
            unit = (size_t)(zr ? 129 : 0)*16640 + j;
        } else {
            int j  = i - 33280;               // [0, 32768)
            int zp = 1 + (j >> 8);            // z' in [1,129)
            int r  = j & 255;
            int c  = r >> 1;
            int xp = (r & 1) ? 129 : 0;
            unit = ((size_t)zp*128 + c)*130 + xp;
        }
        *(i32x4*)&bevin2[unit*8] = i32x4{0,0,0,0};
    }
}

// ---------------- fused projection + bilinear sample + masked mean -> bevin2 ----
// bevin2[z'=z+1][c][x'=x+1][8y] bf16 (padded layout for branch-free conv)
__global__ __launch_bounds__(256) void k_sample(const unsigned short* __restrict__ featT,
                                                const float* __restrict__ mats,
                                                unsigned short* __restrict__ bevin2) {
#pragma clang fp contract(off)
    __shared__ float xch[16][132];        // [vs = y*2+xs][c]
    __shared__ float2 suv[16][6];         // per-voxel per-cam (ux,uy)
    const int tid = threadIdx.x;
    const int b = blockIdx.x;             // 8192 = 128 z * 64 x-pairs
    const int z = b >> 6, x0 = (b & 63) * 2;
    const int cl = tid & 15, vs = tid >> 4;
    // ---- inline projection (exact k_geo arithmetic), 96 threads ----
    if (tid < 96) {
        int v = tid / 6, s = tid - (tid/6)*6;
        int yi = v >> 1, xi2 = x0 + (v & 1);
        float xr = -49.609375f + (float)xi2 * 0.78125f;
        float yr = (-4.9f + 0.625f) + (float)yi * 1.25f;
        float zr = -49.609375f + (float)z * 0.78125f;
        const float* m = mats + s*24;
        float zc = m[8]*xr  + m[9]*yr  + m[10]*zr + m[11];
        float ph = m[12]*xr + m[13]*yr + m[14]*zr + m[15];
        float qh = m[16]*xr + m[17]*yr + m[18]*zr + m[19];
        float denom = fmaxf(zc, 1e-6f);
        float px = ph / denom, py = qh / denom;
        bool valid = (px > -0.5f) & (px < (float)WF - 0.5f) &
                     (py > -0.5f) & (py < (float)HF - 0.5f) & (zc > 0.0f);
        float ux = -10000.0f, uy = -10000.0f;
        if (valid) {
            float gx = 2.0f*px/((float)WF - 1.0f) - 1.0f;
            float gy = 2.0f*py/((float)HF - 1.0f) - 1.0f;
            gx = fminf(fmaxf(gx, -2.0f), 2.0f);
            gy = fminf(fmaxf(gy, -2.0f), 2.0f);
            ux = ((gx + 1.0f)*(float)WF - 1.0f)*0.5f;
            uy = ((gy + 1.0f)*(float)HF - 1.0f)*0.5f;
        }
        suv[v][s] = float2{ux, uy};
    }
    __syncthreads();

    const bf16x8 zz8 = {0,0,0,0,0,0,0,0};
    float sum[8], cnt[8];
#pragma unroll
    for (int k = 0; k < 8; ++k) { sum[k] = 0.0f; cnt[k] = 0.0f; }
    for (int s = 0; s < SNUM; ++s) {
        float2 u = suv[vs][s];
        if (u.x < -999.0f) continue;
        float x0f = floorf(u.x), y0f = floorf(u.y);
        float wx = u.x - x0f, wy = u.y - y0f;
        int ix = (int)x0f, iy = (int)y0f;
        float w00 = (1.0f-wx)*(1.0f-wy), w10 = wx*(1.0f-wy);
        float w01 = (1.0f-wx)*wy,        w11 = wx*wy;
        bool bx0 = (ix >= 0) & (ix < WF);
        bool bx1 = (ix >= -1) & (ix < WF-1);
        bool by0 = (iy >= 0) & (iy < HF);
        bool by1 = (iy >= -1) & (iy < HF-1);
        bool c00 = bx0 & by0, c10 = bx1 & by0, c01 = bx0 & by1, c11 = bx1 & by1;
        const unsigned short* fb = featT + (size_t)s * (HW*CNUM) + cl*8;
        long r0 = (long)(iy*WF + ix) * CNUM;
        bf16x8 v00 = c00 ? *(const bf16x8*)(fb + r0)                 : zz8;
        bf16x8 v10 = c10 ? *(const bf16x8*)(fb + r0 + CNUM)          : zz8;
        bf16x8 v01 = c01 ? *(const bf16x8*)(fb + r0 + WF*CNUM)       : zz8;
        bf16x8 v11 = c11 ? *(const bf16x8*)(fb + r0 + WF*CNUM + CNUM): zz8;
#pragma unroll
        for (int k = 0; k < 8; ++k) {
            float v = 0.0f;
            v = v + w00 * bf2f((unsigned short)v00[k]);
            v = v + w10 * bf2f((unsigned short)v10[k]);
            v = v + w01 * bf2f((unsigned short)v01[k]);
            v = v + w11 * bf2f((unsigned short)v11[k]);
            sum[k] += v;
            cnt[k] += (v != 0.0f) ? 1.0f : 0.0f;
        }
    }
#pragma unroll
    for (int k = 0; k < 8; ++k)
        xch[vs][cl*8 + k] = sum[k] / (1e-6f + cnt[k]);
    __syncthreads();
    // pack: thread t -> channel c = t>>1, xs2 = t&1; one 16B unit (y=0..7)
    {
        int c = tid >> 1, xs2 = tid & 1;
        unsigned pk[4];
#pragma unroll
        for (int j = 0; j < 4; ++j) {
            float v0 = xch[(2*j)*2 + xs2][c];
            float v1 = xch[(2*j+1)*2 + xs2][c];
            pk[j] = (unsigned)f2bf(v0) | ((unsigned)f2bf(v1) << 16);
        }
        size_t unit = ((size_t)(z+1)*128 + c)*130 + (x0 + xs2 + 1);
        *(i32x4*)&bevin2[unit*8] = i32x4{(int)pk[0], (int)pk[1], (int)pk[2], (int)pk[3]};
    }
}

// ---------------- MFMA implicit-GEMM conv 3x3 (r10 structure + psum epilogue) --
// grid (128 z, coh*2+xh) = 512 blocks of 128 thr -> 2 blocks/CU, independent
// barriers. Branch-free padded activations; B via global_load_lds (30.7 KB LDS);
// A (weights) register double-buffered (VGPR ~156, no spill at 1 wave/SIMD).
__global__ __launch_bounds__(128, 1) void k_conv_mfma(
        const unsigned short* __restrict__ bevin2,  // [130 z'][128 c][130 x'][8] bf16
        const unsigned short* __restrict__ w2,      // [tap][co][1024] bf16
        float* __restrict__ out,
        float* __restrict__ psum, float* __restrict__ psq) {
    // [buf][row = dzr*4 + cg][80 units][8]; units 0..65 real, 66..79 dead spill
    __shared__ __align__(16) unsigned short lds[2][12*80*8];
    const int tid  = threadIdx.x;                   // 0..127
    const int z0   = blockIdx.x;
    const int coh  = blockIdx.y >> 1;
    const int xh   = blockIdx.y & 1;
    const int lane = tid & 63, wr = tid >> 6;       // wave id = co-row
    const int co_base = coh*64 + wr*32;
    const int l15 = lane & 15, lhi = lane >> 4;

    f32x4 acc[2][4];
#pragma unroll
    for (int f = 0; f < 2; ++f)
#pragma unroll
        for (int nf = 0; nf < 4; ++nf) acc[f][nf] = f32x4{0.f,0.f,0.f,0.f};

    const unsigned short* aw0 = w2 + ((size_t)(co_base      + l15))*1024 + lhi*8;
    const unsigned short* aw1 = w2 + ((size_t)(co_base + 16 + l15))*1024 + lhi*8;

    bf16x8 afr0[18], afr1[18];

    // wave wr stages rows [6*wr, 6*wr+6); each row: one 16-wide + one 4-wide tail
#define STAGE(BUF, C0)                                                         \
    {                                                                          \
        _Pragma("unroll")                                                      \
        for (int r6 = 0; r6 < 6; ++r6) {                                       \
            int r = wr*6 + r6;                                                 \
            int dzr = r >> 2, cg = r & 3;                                      \
            const unsigned short* gsrc = bevin2 +                              \
                (((size_t)(z0 + dzr)*128 + (C0) + cg)*130 + xh*64)*8;          \
            unsigned short* ldst = &lds[BUF][r*80*8];                          \
            gl_lds16(gsrc + (size_t)lane*8, ldst);                             \
            gl_lds4 (gsrc + 64*8 + (size_t)lane*2, ldst + 64*8);               \
        }                                                                      \
    }
#define A_LOAD(DST, CI0)                                                       \
    {                                                                          \
        _Pragma("unroll")                                                      \
        for (int t = 0; t < 9; ++t) {                                          \
            DST[t*2]   = *(const bf16x8*)(aw0 + (size_t)t*131072 + (CI0));     \
            DST[t*2+1] = *(const bf16x8*)(aw1 + (size_t)t*131072 + (CI0));     \
        }                                                                      \
    }
// 9 taps x 4 nf x 2 co-frags = 72 MFMA, branch-free
#define COMPUTE(BUF, AFR)                                                      \
    {                                                                          \
        __builtin_amdgcn_s_setprio(1);                                         \
        _Pragma("unroll")                                                      \
        for (int dz = 0; dz < 3; ++dz) {                                       \
            _Pragma("unroll")                                                  \
            for (int dx = 0; dx < 3; ++dx) {                                   \
                bf16x8 a0 = AFR[(dz*3+dx)*2];                                  \
                bf16x8 a1 = AFR[(dz*3+dx)*2+1];                                \
                _Pragma("unroll")                                              \
                for (int nf = 0; nf < 4; ++nf) {                               \
                    bf16x8 bfr = *(const bf16x8*)&lds[BUF][((dz*4 + lhi)*80 + nf*16 + l15 + dx)*8]; \
                    acc[0][nf] = __builtin_amdgcn_mfma_f32_16x16x32_bf16(a0, bfr, acc[0][nf], 0, 0, 0); \
                    acc[1][nf] = __builtin_amdgcn_mfma_f32_16x16x32_bf16(a1, bfr, acc[1][nf], 0, 0, 0); \
                }                                                              \
            }                                                                  \
        }                                                                      \
        __builtin_amdgcn_s_setprio(0);                                         \
    }

    // prologue: stage chunk 0 into buf0, load A chunk 0
    STAGE(0, 0);
    A_LOAD(afr0, 0);
    __syncthreads();                       // drains the async staging

    // 32 chunks of 32 ci (4 c-groups each), unrolled by 2
    for (int cc = 0; cc < 16; ++cc) {
        const int k0 = 2*cc;
        STAGE(1, (k0+1)*4);
        A_LOAD(afr1, (k0+1)*32);
        COMPUTE(0, afr0);
        __syncthreads();
        if (cc < 15) {
            STAGE(0, (k0+2)*4);
            A_LOAD(afr0, (k0+2)*32);
        }
        COMPUTE(1, afr1);
        if (cc < 15) __syncthreads();
    }

    // ---- store + instance-norm partials ----
    float ps[2][4], pq[2][4];
#pragma unroll
    for (int f = 0; f < 2; ++f)
#pragma unroll
        for (int r = 0; r < 4; ++r) { ps[f][r] = 0.0f; pq[f][r] = 0.0f; }
#pragma unroll
    for (int f = 0; f < 2; ++f)
#pragma unroll
        for (int nf = 0; nf < 4; ++nf)
#pragma unroll
            for (int r = 0; r < 4; ++r) {
                int co = co_base + f*16 + lhi*4 + r;
                float v = acc[f][nf][r];
                out[(size_t)co*16384 + z0*128 + xh*64 + nf*16 + l15] = v;
                ps[f][r] += v;
                pq[f][r] += v*v;
            }
#pragma unroll
    for (int f = 0; f < 2; ++f)
#pragma unroll
        for (int r = 0; r < 4; ++r) {
            float s = ps[f][r], q = pq[f][r];
#pragma unroll
            for (int m = 1; m < 16; m <<= 1) {
                s += __shfl_xor(s, m);
                q += __shfl_xor(q, m);
            }
            if (l15 == 0) {
                int co = co_base + f*16 + lhi*4 + r;
                int pb = z0*2 + xh;       // 256 partials per co
                psum[co*256 + pb] = s;
                psq [co*256 + pb] = q;
            }
        }
#undef STAGE
#undef A_LOAD
#undef COMPUTE
}

// ---------------- instance-norm stats from partials ----------------
__global__ __launch_bounds__(256) void k_stats(const float* __restrict__ psum,
                                               const float* __restrict__ psq,
                                               float* __restrict__ stats) {
    __shared__ float r1[256], r2[256];
    int co = blockIdx.x, tid = threadIdx.x;
    r1[tid] = psum[co*256 + tid];
    r2[tid] = psq [co*256 + tid];
    __syncthreads();
    for (int off = 128; off > 0; off >>= 1) {
        if (tid < off) { r1[tid] += r1[tid+off]; r2[tid] += r2[tid+off]; }
        __syncthreads();
    }
    if (tid == 0) {
        float mean = r1[0] * (1.0f/16384.0f);
        float var  = r2[0] * (1.0f/16384.0f) - mean*mean;
        stats[co*2]   = mean;
        stats[co*2+1] = rsqrtf(var + 1e-5f);
    }
}

// ---------------- normalize + exact GELU, float4 (in place) ----------------
__global__ __launch_bounds__(256) void k_gelu(float* __restrict__ out,
                                              const float* __restrict__ stats) {
    int i = blockIdx.x*256 + threadIdx.x;      // over 524288 float4s
    int co = i >> 12;                          // 4096 float4s per co
    float mean = stats[co*2], rstd = stats[co*2+1];
    f32x4 v = *(f32x4*)&out[(size_t)i*4];
#pragma unroll
    for (int j = 0; j < 4; ++j) {
        float r = (v[j] - mean) * rstd;
        v[j] = 0.5f * r * (1.0f + erff(r * 0.70710678118654752f));
    }
    *(f32x4*)&out[(size_t)i*4] = v;
}

extern "C" void kernel_launch(void* const* d_in, const int* in_sizes, int n_in,
                              void* d_out, int out_size, void* d_ws, size_t ws_size,
                              hipStream_t stream) {
    const float* cam_feat = (const float*)d_in[0];
    const float* intrins  = (const float*)d_in[1];
    const float* rots     = (const float*)d_in[2];
    const float* trans    = (const float*)d_in[3];
    const float* conv_w   = (const float*)d_in[4];
    float* out = (float*)d_out;
    float* ws  = (float*)d_ws;

    float* mats  = ws;                                          // 160 f
    unsigned short* featT  = (unsigned short*)(ws + 160);       // 4,300,800 bf16
    unsigned short* bevin2 = featT + (size_t)SNUM*HW*CNUM;      // 17,305,600 bf16
    unsigned short* w2     = bevin2 + (size_t)130*128*130*8;    // 1,179,648 bf16
    float* psum  = (float*)(w2 + 9*128*1024);                   // 32768 f
    float* psq   = psum + 32768;                                // 32768 f
    float* stats = psq + 32768;                                 // 256 f
    // total ~46 MB

    hipLaunchKernelGGL(k_setup, dim3(1), dim3(64), 0, stream, intrins, rots, trans, mats);
    hipLaunchKernelGGL(k_tfeat, dim3(HW/32, CNUM/32, SNUM), dim3(32,8), 0, stream, cam_feat, featT);
    hipLaunchKernelGGL(k_prep, dim3(4608 + 258), dim3(256), 0, stream, conv_w, w2, bevin2);
    hipLaunchKernelGGL(k_sample, dim3(8192), dim3(256), 0, stream, featT, mats, bevin2);
    hipLaunchKernelGGL(k_conv_mfma, dim3(128, 4), dim3(128), 0, stream, bevin2, w2, out, psum, psq);
    hipLaunchKernelGGL(k_stats, dim3(128), dim3(256), 0, stream, psum, psq, stats);
    hipLaunchKernelGGL(k_gelu, dim3(2048), dim3(256), 0, stream, out, stats);
}